// Round 5
// baseline (107.998 us; speedup 1.0000x reference)
//
#include <hip/hip_runtime.h>

// Problem constants (from reference setup_inputs)
#define LATDIM 128     // d
#define ANUM   64      // anchor sets A
#define NNODES 10000   // N
#define PERIOD 625     // period of (64*i mod 10000); gcd(64,10000)=16
#define NJ     16      // outputs per block: n = s + 625*j, j in [0,16)

// ---------------------------------------------------------------------------
// Verified algebra (r3..r11 passed, absmax 9.8e-4):
//   out[n,o] = b[o] + (1/A)*( sum_k G[n,k]*W[o,k] + sum_k S[s,k]*W[o,128+k] )
//     s = n mod 625
//     G[n,k] = sum_a dists[a,n]*E[anchor[a],k]
//     S[s,k] = sum_{r in [64s,64s+64) mod N} E[r,k]
//
// r12 delta: r11 calibration (r10: kernel 152, dur 210 -> fixed 58us =
// fill 40.6 + 17.4 overhead) => r11's fused kernel ~30us. Bottlenecks:
// 3 blocks/CU (12 waves, LDS 44.75KB cap), ~500 ds_read/thread LDS-pipe
// pressure, pointless 32KB EA staging. Changes:
//   1) EA read per-lane DIRECT from global (coalesced 512B/wave, L2-hot,
//      reused by all 625 blocks) -> LDS 12.8KB, staging phase deleted.
//   2) __launch_bounds__(256,6): 6 blocks/CU, 24 waves (2x TLP).
//   3) final GEMM register-blocked 2-o-per-lane (k-half h = o&1, pair
//      lanes reduce via ONE __shfl_xor) -> G reads 272->144/thread, no
//      R buffer, one less sync, stores stay coalesced.
// One plain launch, no workspace, no barriers (r10 proved grid barriers
// cost ~140us; r5 agrees).
// ---------------------------------------------------------------------------

__global__ __launch_bounds__(256, 6) void fused_kernel(
    const float* __restrict__ embeds,   // [N, d] fp32
    const float* __restrict__ dists,    // [A, N] fp32
    const float* __restrict__ W,        // [d, 2d] fp32 row-major
    const float* __restrict__ b,        // [d] fp32
    const int*   __restrict__ anchor,   // [A] int32
    float* __restrict__ out)            // [N, d] fp32
{
    __shared__ float G_s[NJ * LATDIM];   // 8 KB (first 4 KB = Xp scratch early)
    __shared__ float D_s[ANUM * NJ];     // 4 KB
    __shared__ float S_s[LATDIM];        // 512 B
    __shared__ int   An[ANUM];           // 256 B   (12.75 KB total)

    const int tid = threadIdx.x;
    // bijective XCD swizzle (625 = 8*78+1, q=78 r=1): consecutive s per XCD
    const int orig = blockIdx.x;
    const int xcd = orig & 7, ii = orig >> 3;
    const int s = (xcd == 0) ? ii : (79 + (xcd - 1) * 78 + ii);

    // ---- phase 0: stage anchor ids, dists gather, S row-group partials ----
    if (tid < ANUM) An[tid] = anchor[tid];
    #pragma unroll
    for (int it = 0; it < 4; ++it) {
        int idx = it * 256 + tid;           // 0..1023
        int a = idx >> 4, j = idx & 15;     // n_j = s + 625*j <= 9999
        D_s[a * NJ + j] = dists[(size_t)a * NNODES + (s + PERIOD * j)];
    }
    float (*Xp)[LATDIM] = (float (*)[LATDIM])G_s;   // 4 KB scratch in G_s
    {
        const int row0 = (64 * s) % NNODES;         // span [row0, row0+64)
        const int c4 = tid & 31, hg = tid >> 5;
        float4 sum = {0.f, 0.f, 0.f, 0.f};
        #pragma unroll
        for (int i = 0; i < 8; ++i) {
            int row = row0 + 8 * i + hg;
            if (row >= NNODES) row -= NNODES;       // single wrap suffices
            float4 v = *((const float4*)(embeds + (size_t)row * LATDIM) + c4);
            sum.x += v.x; sum.y += v.y; sum.z += v.z; sum.w += v.w;
        }
        ((float4*)&Xp[hg][0])[c4] = sum;
    }
    __syncthreads();        // sync1: An, D_s, Xp ready

    // ---- S combine (tid<128) — reads Xp (G_s scratch), writes S_s ----
    if (tid < LATDIM) {
        float t = Xp[0][tid];
        #pragma unroll
        for (int g = 1; g < 8; ++g) t += Xp[g][tid];
        S_s[tid] = t;
    }

    // ---- G[j,k] = sum_a D[a,j] * E[An[a],k]  (accumulate in registers) ----
    {
        const int k  = tid & 127;           // per-lane k: coalesced E reads
        const int jh = tid >> 7;            // wave-uniform j-octet
        float g[8] = {};
        #pragma unroll 8
        for (int a = 0; a < ANUM; ++a) {
            const float ea = embeds[(size_t)An[a] * LATDIM + k];  // L2-hot
            const float4 d0 = ((const float4*)(D_s + a * NJ + jh * 8))[0]; // bcast
            const float4 d1 = ((const float4*)(D_s + a * NJ + jh * 8))[1]; // bcast
            g[0] += d0.x * ea; g[1] += d0.y * ea;
            g[2] += d0.z * ea; g[3] += d0.w * ea;
            g[4] += d1.x * ea; g[5] += d1.y * ea;
            g[6] += d1.z * ea; g[7] += d1.w * ea;
        }
        __syncthreads();    // sync2: all Xp readers (S combine) done
        #pragma unroll
        for (int jj = 0; jj < 8; ++jj)
            G_s[(jh * 8 + jj) * LATDIM + k] = g[jj];   // stride-1: 2/bank, free
    }
    __syncthreads();        // sync3: G_s, S_s ready

    // ---- final: out[s+625j, o] = b[o] + (G[j]·W1(o) + S·W2(o))/A ----
    // Lane owns o = tid&127; lane-pair (o^1) shares two W rows {o&~1, o|1};
    // lane's k-half is h = o&1; one shfl_xor(.,1) completes split-k.
    {
        const int o  = tid & 127;
        const int h  = tid & 1;             // k-half (== o&1)
        const int jg = tid >> 7;            // j-octet
        const float4* Wf4 = (const float4*)W;            // [128][64] float4
        const float4* w1p = Wf4 + (size_t)(o & ~1) * 64 + h * 16;  // W1 half
        const float4* w2p = w1p + 32;                               // W2 half
        const float4* G4  = (const float4*)G_s;
        const float4* S4  = (const float4*)S_s;

        float acc[16] = {};                 // [jj][row r], r=0: o&~1, r=1: o|1
        float sacc0 = 0.f, sacc1 = 0.f;
        #pragma unroll 4
        for (int q = 0; q < 16; ++q) {
            const float4 wa = w1p[q];       // row o&~1 (L1/L2-hot)
            const float4 wb = w1p[64 + q];  // row o|1
            const float4 va = w2p[q];
            const float4 vb = w2p[64 + q];
            const float4 sv = S4[h * 16 + q];               // 2-addr/wave: free
            sacc0 += sv.x*va.x + sv.y*va.y + sv.z*va.z + sv.w*va.w;
            sacc1 += sv.x*vb.x + sv.y*vb.y + sv.z*vb.z + sv.w*vb.w;
            #pragma unroll
            for (int jj = 0; jj < 8; ++jj) {
                const float4 gv = G4[(jg * 8 + jj) * 32 + h * 16 + q];
                acc[jj*2+0] += gv.x*wa.x + gv.y*wa.y + gv.z*wa.z + gv.w*wa.w;
                acc[jj*2+1] += gv.x*wb.x + gv.y*wb.y + gv.z*wb.z + gv.w*wb.w;
            }
        }

        // pair reduction: lane keeps its own row (r == h). Cross-supply so
        // each lane receives the partner's half for ITS row.
        const float bias = b[o];
        float s_mine = h ? sacc1 : sacc0;
        float s_src  = h ? sacc0 : sacc1;
        float s_full = s_mine + __shfl_xor(s_src, 1);
        #pragma unroll
        for (int jj = 0; jj < 8; ++jj) {
            float m  = h ? acc[jj*2+1] : acc[jj*2+0];   // own row, own half
            float xs = h ? acc[jj*2+0] : acc[jj*2+1];   // partner's row, own half
            float gfull = m + __shfl_xor(xs, 1);
            const int n = s + PERIOD * (jg * 8 + jj);
            out[(size_t)n * LATDIM + o] =
                bias + (gfull + s_full) * (1.0f / ANUM);
        }
    }
}

extern "C" void kernel_launch(void* const* d_in, const int* in_sizes, int n_in,
                              void* d_out, int out_size, void* d_ws, size_t ws_size,
                              hipStream_t stream) {
    const float* embeds = (const float*)d_in[0];   // [10000,128] fp32
    const float* dists  = (const float*)d_in[1];   // [64,10000]  fp32
    const float* W      = (const float*)d_in[2];   // [128,256]   fp32
    const float* b      = (const float*)d_in[3];   // [128]       fp32
    const int*   anchor = (const int*)d_in[4];     // [64]        int32
    float* out = (float*)d_out;                    // [10000,128] fp32

    (void)d_ws; (void)ws_size;   // no workspace, no barrier, no memset
    fused_kernel<<<PERIOD, 256, 0, stream>>>(embeds, dists, W, b, anchor, out);
}

// Round 6
// 94.590 us; speedup vs baseline: 1.1417x; 1.1417x over previous
//
#include <hip/hip_runtime.h>

// Problem constants (from reference setup_inputs)
#define LATDIM 128     // d
#define ANUM   64      // anchor sets A
#define NNODES 10000   // N
#define PERIOD 625     // period of (64*i mod 10000); gcd(64,10000)=16
#define JB     8       // j's per block: n = s + 625*(jhalf*8 + j8)
#define NB     1250    // 2 blocks per residue s

// ---------------------------------------------------------------------------
// Verified algebra (r3..r12 passed, absmax 9.8e-4):
//   out[n,o] = b[o] + (1/A)*( sum_k G[n,k]*W[o,k] + sum_k S[s,k]*W[o,128+k] )
//     s = n mod 625
//     G[n,k] = sum_a dists[a,n]*E[anchor[a],k]
//     S[s,k] = sum_{r in [64s,64s+64) mod N} E[r,k]
//
// r13 delta: fix r12's two regressions, attack the REAL limiter.
//   - r12 post-mortem: launch_bounds(256,6) clamped VGPR to 40 -> scratch
//     spills (WRITE 17MB vs 5.1MB out, FETCH +5MB) and the shfl pair-
//     reduction added 1.44M bank conflicts. Kernel 30->52us. Reverted both:
//     plain __launch_bounds__(256), r11's split-k + R_s reduction.
//   - real limiter: grid 625 = 2.44 blocks/CU. Split each s into TWO blocks
//     (j-halves): 1250 blocks = 4.88 blocks/CU ~ 19.5 waves/CU (2x TLP).
//     Window sum duplicated per pair (cheap: 32KB L2-hot + 1k adds).
//   - LDS 10.75KB; EA stays direct-from-global (L2-hot, hidden by TLP).
//   - bijective XCD swizzle over 1250 units (q=156, r=2): pair (2s,2s+1)
//     and consecutive s on one XCD -> dists-line + embeds-window L2 reuse.
// One plain launch, no workspace, no barriers.
// ---------------------------------------------------------------------------

__global__ __launch_bounds__(256) void fused_kernel(
    const float* __restrict__ embeds,   // [N, d] fp32
    const float* __restrict__ dists,    // [A, N] fp32
    const float* __restrict__ W,        // [d, 2d] fp32 row-major
    const float* __restrict__ b,        // [d] fp32
    const int*   __restrict__ anchor,   // [A] int32
    float* __restrict__ out)            // [N, d] fp32
{
    __shared__ float G_s[JB * LATDIM];   // 4 KB (aliased as Xp in phase 0)
    __shared__ float R_s[JB * LATDIM];   // 4 KB split-k partials
    __shared__ float D_s[ANUM * JB];     // 2 KB
    __shared__ float S_s[LATDIM];        // 512 B
    __shared__ int   An[ANUM];           // 256 B  (10.75 KB total)

    const int tid = threadIdx.x;
    // bijective XCD swizzle over NB=1250 = 8*156 + 2 (m204 form, q=156 r=2)
    const int orig = blockIdx.x;
    const int xcd = orig & 7, ii = orig >> 3;
    const int u = (xcd < 2) ? (xcd * 157 + ii)
                            : (2 * 157 + (xcd - 2) * 156 + ii);
    const int s = u >> 1;               // 0..624
    const int jhalf = u & 1;            // which 8-j half

    // ---- phase 0: anchor ids, dists gather (8 j's), S row-group partials ----
    if (tid < ANUM) An[tid] = anchor[tid];
    #pragma unroll
    for (int it = 0; it < 2; ++it) {
        int idx = it * 256 + tid;           // 0..511
        int a = idx >> 3, j8 = idx & 7;     // n = s+625*(jhalf*8+j8) <= 9999
        D_s[a * JB + j8] =
            dists[(size_t)a * NNODES + (s + PERIOD * (jhalf * JB + j8))];
    }
    float (*Xp)[LATDIM] = (float (*)[LATDIM])G_s;   // 4 KB scratch in G_s
    {
        const int row0 = (64 * s) % NNODES;         // span [row0, row0+64)
        const int c4 = tid & 31, hg = tid >> 5;
        float4 sum = {0.f, 0.f, 0.f, 0.f};
        #pragma unroll
        for (int i = 0; i < 8; ++i) {
            int row = row0 + 8 * i + hg;
            if (row >= NNODES) row -= NNODES;       // single wrap suffices
            float4 v = *((const float4*)(embeds + (size_t)row * LATDIM) + c4);
            sum.x += v.x; sum.y += v.y; sum.z += v.z; sum.w += v.w;
        }
        ((float4*)&Xp[hg][0])[c4] = sum;
    }
    __syncthreads();        // sync1: An, D_s, Xp ready

    // ---- S combine (tid<128): reads Xp (G_s alias), writes S_s ----
    if (tid < LATDIM) {
        float t = Xp[0][tid];
        #pragma unroll
        for (int g = 1; g < 8; ++g) t += Xp[g][tid];
        S_s[tid] = t;
    }

    // ---- G[j,k] = sum_a D[a,j] * E[An[a],k] (registers; no LDS writes yet) ----
    {
        const int k  = tid & 127;           // per-lane k: coalesced E reads
        const int jq = tid >> 7;            // wave-uniform j-quartet (0/1)
        float g[4] = {};
        #pragma unroll 8
        for (int a = 0; a < ANUM; ++a) {
            const float ea = embeds[(size_t)An[a] * LATDIM + k];   // L2-hot
            const float4 d = ((const float4*)(D_s + a * JB))[jq];  // bcast
            g[0] += d.x * ea; g[1] += d.y * ea;
            g[2] += d.z * ea; g[3] += d.w * ea;
        }
        __syncthreads();    // sync2: Xp readers (S combine) done
        #pragma unroll
        for (int jj = 0; jj < 4; ++jj)
            G_s[(jq * 4 + jj) * LATDIM + k] = g[jj];   // stride-1: free
    }
    __syncthreads();        // sync3: G_s, S_s ready

    // ---- final: out[n,o] = b[o] + (G[j]·W1(o) + S·W2(o))/A, split-k ----
    {
        const int o = tid & 127;            // output channel
        const int h = tid >> 7;             // split-k half, wave-uniform
        const float4* Wr1 = (const float4*)(W + (size_t)o * (2 * LATDIM) + h * 64);
        const float4* Wr2 = Wr1 + 32;       // second W half, same o row
        const float4* S4  = (const float4*)S_s;
        const float4* G4  = (const float4*)G_s;
        float acc[JB] = {};
        float sacc = 0.f;
        #pragma unroll 4
        for (int q = 0; q < 16; ++q) {
            const float4 w1 = Wr1[q];               // L1/L2-hot W row
            const float4 w2 = Wr2[q];
            const float4 sv = S4[h * 16 + q];       // LDS broadcast
            sacc += sv.x*w2.x + sv.y*w2.y + sv.z*w2.z + sv.w*w2.w;
            #pragma unroll
            for (int j = 0; j < JB; ++j) {
                const float4 gv = G4[j * 32 + h * 16 + q];  // LDS broadcast
                acc[j] += gv.x*w1.x + gv.y*w1.y + gv.z*w1.z + gv.w*w1.w;
            }
        }
        if (h == 1) {
            #pragma unroll
            for (int j = 0; j < JB; ++j)
                R_s[j * LATDIM + o] = acc[j] + sacc;
        }
        __syncthreads();
        if (h == 0) {
            const float bias = b[o];
            #pragma unroll
            for (int j = 0; j < JB; ++j) {
                const int n = s + PERIOD * (jhalf * JB + j);
                out[(size_t)n * LATDIM + o] =
                    bias + (acc[j] + sacc + R_s[j * LATDIM + o]) * (1.0f / ANUM);
            }
        }
    }
}

extern "C" void kernel_launch(void* const* d_in, const int* in_sizes, int n_in,
                              void* d_out, int out_size, void* d_ws, size_t ws_size,
                              hipStream_t stream) {
    const float* embeds = (const float*)d_in[0];   // [10000,128] fp32
    const float* dists  = (const float*)d_in[1];   // [64,10000]  fp32
    const float* W      = (const float*)d_in[2];   // [128,256]   fp32
    const float* b      = (const float*)d_in[3];   // [128]       fp32
    const int*   anchor = (const int*)d_in[4];     // [64]        int32
    float* out = (float*)d_out;                    // [10000,128] fp32

    (void)d_ws; (void)ws_size;   // no workspace, no barrier, no memset
    fused_kernel<<<NB, 256, 0, stream>>>(embeds, dists, W, b, anchor, out);
}

// Round 7
// 84.667 us; speedup vs baseline: 1.2756x; 1.1172x over previous
//
#include <hip/hip_runtime.h>

// Problem constants (from reference setup_inputs)
#define LATDIM 128     // d
#define ANUM   64      // anchor sets A
#define NNODES 10000   // N
#define PERIOD 625     // period of (64*i mod 10000); gcd(64,10000)=16
#define NJ     16      // outputs per block: n = s + 625*j, j in [0,16)

// ---------------------------------------------------------------------------
// Verified algebra (r3..r13 passed, absmax 9.8e-4):
//   out[n,o] = b[o] + (1/A)*( sum_a dists[a,n]*P[a,o] + sum_k S[s,k]*W[o,128+k] )
//     s = n mod 625
//     P[a,o] = sum_k E[anchor[a],k]*W[o,k]
//     S[s,k] = sum_{r in [64s,64s+64) mod N} E[r,k]
//
// r14 delta: BACK TO TWO KERNELS — the trajectory says two-kernel ≈ 81.5
// (r0/r1/r8) vs fused 88-95 (r11/r12/r13). With fixed overhead ~57us
// (r10/r12 calibration), the marginal cost of a 2nd launch is only ~5-7us,
// while fusion forced the G-route's redundant W/EA traffic (+13us kernel).
//   k1: P only — 64 tiny blocks (r10's verified A'-phase verbatim).
//       T2b global round-trip deleted.
//   k2: block := residue s. Own window sum + local T2 (r11/r13 verified
//       phases), P staged 32KB LDS + D_s gather + wave-uniform broadcast
//       acc loop (r8-main verified pattern). W2-half read once per block
//       (40MB L2 total vs fused r13's 160MB).
// r12 lessons kept: no launch_bounds minimum (spills), no shfl reduction
// (bank conflicts). r10 lesson: no cross-block sync.
// ---------------------------------------------------------------------------

__global__ __launch_bounds__(256) void p_kernel(
    const float* __restrict__ embeds,   // [N, d]
    const float* __restrict__ W,        // [d, 2d] row-major
    const int*   __restrict__ anchor,   // [A]
    float* __restrict__ P)              // [A, d] (ws)
{
    __shared__ float X_s[LATDIM];
    __shared__ float R_s[LATDIM];
    const int tid = threadIdx.x;
    const int a = blockIdx.x;           // 0..63
    if (tid < 32)
        ((float4*)X_s)[tid] =
            *((const float4*)(embeds + (size_t)anchor[a] * LATDIM) + tid);
    __syncthreads();
    const int o = tid & 127, h = tid >> 7;
    const float4* Wr = (const float4*)(W + (size_t)o * (2 * LATDIM) + h * 64);
    const float4* X4 = (const float4*)X_s;
    float acc = 0.f;
    #pragma unroll
    for (int q = 0; q < 16; ++q) {
        float4 w4 = Wr[q], x4 = X4[h * 16 + q];
        acc += w4.x*x4.x + w4.y*x4.y + w4.z*x4.z + w4.w*x4.w;
    }
    if (h == 1) R_s[o] = acc;
    __syncthreads();
    if (h == 0) P[(size_t)a * LATDIM + o] = acc + R_s[o];
}

__global__ __launch_bounds__(256) void main_kernel(
    const float* __restrict__ embeds,   // [N, d]
    const float* __restrict__ dists,    // [A, N]
    const float* __restrict__ W,        // [d, 2d] row-major
    const float* __restrict__ b,        // [d]
    const float* __restrict__ P,        // [A, d] (ws, from p_kernel)
    float* __restrict__ out)            // [N, d]
{
    __shared__ float P_s[ANUM * LATDIM];   // 32 KB
    __shared__ float Xp[8][LATDIM];        // 4 KB window partials
    __shared__ float D_s[ANUM * NJ];       // 4 KB dists gather
    __shared__ float S_s[LATDIM];          // 512 B
    __shared__ float T2_s[LATDIM];         // 512 B
    __shared__ float Rb[LATDIM];           // 512 B  (~41.5 KB total)

    const int tid = threadIdx.x;
    // bijective XCD swizzle over 625 = 8*78+1 (verified r11): consecutive s
    // per XCD -> dists lines (16 consecutive s share a 64B line) + embeds
    // windows stay L2-local.
    const int orig = blockIdx.x;
    const int xcd = orig & 7, ii = orig >> 3;
    const int s = (xcd == 0) ? ii : (79 + (xcd - 1) * 78 + ii);

    // ---- phase 0: stage P (coalesced), D gather, window partials ----
    {
        float4* P4 = (float4*)P_s; const float4* Pg = (const float4*)P;
        #pragma unroll
        for (int it = 0; it < 8; ++it)      // 2048 float4 / 256 thr
            P4[it * 256 + tid] = Pg[it * 256 + tid];
    }
    #pragma unroll
    for (int it = 0; it < 4; ++it) {        // 1024 scalars / 256 thr
        int idx = it * 256 + tid;
        int a = idx >> 4, j = idx & 15;     // n_j = s + 625*j <= 9999
        D_s[a * NJ + j] = dists[(size_t)a * NNODES + (s + PERIOD * j)];
    }
    {
        const int row0 = (64 * s) % NNODES;     // span [row0, row0+64)
        const int c4 = tid & 31, hg = tid >> 5;
        float4 sum = {0.f, 0.f, 0.f, 0.f};
        #pragma unroll
        for (int i = 0; i < 8; ++i) {
            int row = row0 + 8 * i + hg;
            if (row >= NNODES) row -= NNODES;   // single wrap suffices
            float4 v = *((const float4*)(embeds + (size_t)row * LATDIM) + c4);
            sum.x += v.x; sum.y += v.y; sum.z += v.z; sum.w += v.w;
        }
        ((float4*)&Xp[hg][0])[c4] = sum;
    }
    __syncthreads();        // P_s, D_s, Xp ready

    // ---- S combine (tid<128) ----
    if (tid < LATDIM) {
        float t = Xp[0][tid];
        #pragma unroll
        for (int g = 1; g < 8; ++g) t += Xp[g][tid];
        S_s[tid] = t;
    }
    __syncthreads();        // S_s ready

    // ---- T2[o] = b[o] + (S · W2(o))/A, split-k across halves ----
    {
        const int o = tid & 127, h = tid >> 7;
        const float4* Wr2 =
            (const float4*)(W + (size_t)o * (2 * LATDIM) + LATDIM + h * 64);
        const float4* S4 = (const float4*)S_s;
        float sacc = 0.f;
        #pragma unroll
        for (int q = 0; q < 16; ++q) {
            float4 w4 = Wr2[q], sv = S4[h * 16 + q];    // LDS broadcast
            sacc += w4.x*sv.x + w4.y*sv.y + w4.z*sv.z + w4.w*sv.w;
        }
        if (h == 1) Rb[o] = sacc;
        __syncthreads();
        if (h == 0) T2_s[o] = b[o] + (sacc + Rb[o]) * (1.0f / ANUM);
    }
    __syncthreads();        // T2_s ready

    // ---- acc loop (r8-main pattern): wave-uniform D broadcasts ----
    const int lane = tid & 63;
    const int w    = __builtin_amdgcn_readfirstlane(tid >> 6);  // 0..3
    const int o    = (w & 1) * 64 + lane;   // output channel
    const int nc   = w >> 1;                // j-octet (0/1)
    float acc[8] = {};
    #pragma unroll 8
    for (int a = 0; a < ANUM; ++a) {
        const float p = P_s[a * LATDIM + o];    // stride-1: 2/bank, free
        const float4 d0 = ((const float4*)(D_s + a * NJ + nc * 8))[0]; // bcast
        const float4 d1 = ((const float4*)(D_s + a * NJ + nc * 8))[1]; // bcast
        acc[0] += d0.x * p; acc[1] += d0.y * p;
        acc[2] += d0.z * p; acc[3] += d0.w * p;
        acc[4] += d1.x * p; acc[5] += d1.y * p;
        acc[6] += d1.z * p; acc[7] += d1.w * p;
    }

    const float t2 = T2_s[o];
    #pragma unroll
    for (int j = 0; j < 8; ++j) {
        const int n = s + PERIOD * (nc * 8 + j);
        out[(size_t)n * LATDIM + o] = acc[j] * (1.0f / ANUM) + t2;
    }
}

extern "C" void kernel_launch(void* const* d_in, const int* in_sizes, int n_in,
                              void* d_out, int out_size, void* d_ws, size_t ws_size,
                              hipStream_t stream) {
    const float* embeds = (const float*)d_in[0];   // [10000,128] fp32
    const float* dists  = (const float*)d_in[1];   // [64,10000]  fp32
    const float* W      = (const float*)d_in[2];   // [128,256]   fp32
    const float* b      = (const float*)d_in[3];   // [128]       fp32
    const int*   anchor = (const int*)d_in[4];     // [64]        int32
    float* out = (float*)d_out;                    // [10000,128] fp32

    float* P = (float*)d_ws;              // 64*128 floats = 32 KB

    p_kernel<<<ANUM, 256, 0, stream>>>(embeds, W, anchor, P);
    main_kernel<<<PERIOD, 256, 0, stream>>>(embeds, dists, W, b, P, out);
}

// Round 8
// 80.638 us; speedup vs baseline: 1.3393x; 1.0500x over previous
//
#include <hip/hip_runtime.h>

// Problem constants (from reference setup_inputs)
#define LATDIM 128     // d
#define ANUM   64      // anchor sets A
#define NNODES 10000   // N
#define PERIOD 625     // period of (64*i mod 10000); gcd(64,10000)=16
#define TN     8       // n per main block (10000 = 1250 * 8, no tail)
#define NB2    1250    // main grid
#define ABLK   64      // P blocks in prep

// ---------------------------------------------------------------------------
// Verified algebra (r3..r14 passed, absmax 9.8e-4):
//   out[n,o] = b[o] + (1/A)*( sum_a dists[a,n]*P[a,o] + sum_k S[s,k]*W[o,128+k] )
//     s = n mod 625
//     P[a,o] = sum_k E[anchor[a],k]*W[o,k]
//     S[s,k] = sum_{r in [64s,64s+64) mod N} E[r,k]
//
// r15 delta: calibration r10/r12 shows fixed ~57us INDEPENDENT of launch
// count -> only summed GPU time matters. r14's main regressed (27.7us
// kernels) from a 6-phase serial chain at 2.44 blocks/CU against a cold
// L2/L3 (the 256MB poison fill evicts everything). Fix:
//   k1: r1/r8 prep VERBATIM (689 blocks: 64 P + 625 T2b) — measured-good.
//   k2: ZERO-LDS, ZERO-sync main. p = P[a*128+o] direct global (256B
//       coalesced, L1-hot, P=32KB shared by all blocks); dists via
//       wave-uniform s_loads (r0 idiom); T2b added direct from global in
//       epilogue. TN=8 -> 1250 blocks = 4.9/CU = ~20 waves/CU (2x r14 TLP,
//       1/3 the phases). VGPR ~32.
//   XCD swizzle on k2 (1250=8*156+2, r13-verified bijective form).
// Lessons kept: no launch_bounds minimum (r12 spills), no shfl reduction
// (r12 conflicts), no cross-block sync (r10), no redundant W/EA (r11/r13).
// ---------------------------------------------------------------------------

__global__ __launch_bounds__(256) void prep_kernel(
    const float* __restrict__ embeds,   // [N, d] fp32
    const float* __restrict__ W,        // [d, 2d] fp32 row-major
    const float* __restrict__ b,        // [d] fp32
    const int*   __restrict__ anchor,   // [A] int32
    float* __restrict__ P,              // [A, d]   (ws)
    float* __restrict__ T2b)            // [625, d] (ws)
{
    __shared__ float X_s[LATDIM];       // 512 B
    __shared__ float R_s[LATDIM];       // 512 B
    __shared__ float Xp[8][LATDIM];     // 4 KB
    const int tid = threadIdx.x;
    const float4* X_s4 = (const float4*)X_s;

    if (blockIdx.x < ABLK) {
        // ---- P[a,:] = E[anchor[a],:] @ W[:, 0:128] ----
        const int a = blockIdx.x;
        if (tid < 32) {
            ((float4*)X_s)[tid] =
                *((const float4*)(embeds + (size_t)anchor[a] * LATDIM) + tid);
        }
        __syncthreads();

        const int o = tid & 127;
        const int h = tid >> 7;
        const float4* Wr = (const float4*)(W + (size_t)o * (2 * LATDIM) + h * 64);
        float acc = 0.f;
        #pragma unroll
        for (int k4 = 0; k4 < 16; ++k4) {
            float4 w4 = Wr[k4];
            float4 x4 = X_s4[h * 16 + k4];      // LDS broadcast
            acc += w4.x*x4.x + w4.y*x4.y + w4.z*x4.z + w4.w*x4.w;
        }
        if (h == 1) R_s[o] = acc;
        __syncthreads();
        if (h == 0) P[(size_t)a * LATDIM + o] = acc + R_s[o];
    } else {
        // ---- T2b[s,:] = b + (1/A) * S[s,:] @ W[:, 128:256] ----
        const int s = blockIdx.x - ABLK;        // 0..624
        const int row0 = (64 * s) % NNODES;     // contiguous span start

        const int c4 = tid & 31;                // float4 column 0..31
        const int hg = tid >> 5;                // row group 0..7
        float4 sum = {0.f, 0.f, 0.f, 0.f};
        #pragma unroll
        for (int i = 0; i < 8; ++i) {
            int row = row0 + 8 * i + hg;
            if (row >= NNODES) row -= NNODES;   // single wrap suffices
            float4 v = *((const float4*)(embeds + (size_t)row * LATDIM) + c4);
            sum.x += v.x; sum.y += v.y; sum.z += v.z; sum.w += v.w;
        }
        ((float4*)&Xp[hg][0])[c4] = sum;
        __syncthreads();
        if (tid < LATDIM) {                     // conflict-free combine
            float t = Xp[0][tid];
            #pragma unroll
            for (int g = 1; g < 8; ++g) t += Xp[g][tid];
            X_s[tid] = t;
        }
        __syncthreads();

        const int o = tid & 127;
        const int h = tid >> 7;
        const float4* Wr =
            (const float4*)(W + (size_t)o * (2 * LATDIM) + LATDIM + h * 64);
        float acc = 0.f;
        #pragma unroll
        for (int k4 = 0; k4 < 16; ++k4) {
            float4 w4 = Wr[k4];
            float4 x4 = X_s4[h * 16 + k4];      // LDS broadcast
            acc += w4.x*x4.x + w4.y*x4.y + w4.z*x4.z + w4.w*x4.w;
        }
        if (h == 1) R_s[o] = acc;
        __syncthreads();
        if (h == 0)
            T2b[(size_t)s * LATDIM + o] =
                b[o] + (acc + R_s[o]) * (1.0f / ANUM);
    }
}

// out[n,o] = (1/A) * sum_a dists[a,n] * P[a,o] + T2b[n%625, o]
// ZERO LDS, ZERO syncthreads: P via L1-hot coalesced global reads, dists
// via wave-uniform scalar loads, T2b direct in epilogue.
__global__ __launch_bounds__(256) void main_kernel(
    const float* __restrict__ dists,    // [A, N] fp32
    const float* __restrict__ P,        // [A, d]
    const float* __restrict__ T2b,      // [625, d]
    float* __restrict__ out)            // [N, d] fp32
{
    const int tid = threadIdx.x;
    // bijective XCD swizzle over 1250 = 8*156 + 2 (r13-verified form):
    // consecutive n-tiles on one XCD -> dists-line + T2b-row L2 reuse.
    const int orig = blockIdx.x;
    const int xcd = orig & 7, ii = orig >> 3;
    const int u = (xcd < 2) ? (xcd * 157 + ii)
                            : (314 + (xcd - 2) * 156 + ii);

    const int lane = tid & 63;
    const int w    = __builtin_amdgcn_readfirstlane(tid >> 6);  // uniform 0..3
    const int o    = (w & 1) * 64 + lane;   // output channel
    const int nc   = w >> 1;                // n-quad within tile (0/1)
    const int nb   = u * TN + nc * 4;       // uniform; always in-range

    const float* __restrict__ Pcol = P + o;
    float acc[4] = {};
    #pragma unroll 8
    for (int a = 0; a < ANUM; ++a) {
        const float p = Pcol[(size_t)a * LATDIM];            // L1-hot, 256B/wave
        const float* __restrict__ drow = dists + (size_t)a * NNODES + nb;
        acc[0] += drow[0] * p;                               // uniform s_loads
        acc[1] += drow[1] * p;
        acc[2] += drow[2] * p;
        acc[3] += drow[3] * p;
    }

    #pragma unroll
    for (int j = 0; j < 4; ++j) {
        const int n = nb + j;
        const int s = n % PERIOD;
        out[(size_t)n * LATDIM + o] =
            acc[j] * (1.0f / ANUM) + T2b[(size_t)s * LATDIM + o];
    }
}

extern "C" void kernel_launch(void* const* d_in, const int* in_sizes, int n_in,
                              void* d_out, int out_size, void* d_ws, size_t ws_size,
                              hipStream_t stream) {
    const float* embeds = (const float*)d_in[0];   // [10000,128] fp32
    const float* dists  = (const float*)d_in[1];   // [64,10000]  fp32
    const float* W      = (const float*)d_in[2];   // [128,256]   fp32
    const float* b      = (const float*)d_in[3];   // [128]       fp32
    const int*   anchor = (const int*)d_in[4];     // [64]        int32
    float* out = (float*)d_out;                    // [10000,128] fp32

    float* P   = (float*)d_ws;            // 64*128 floats   = 32 KB
    float* T2b = P + ANUM * LATDIM;       // 625*128 floats  = 320 KB

    prep_kernel<<<ABLK + PERIOD, 256, 0, stream>>>(embeds, W, b, anchor, P, T2b);
    main_kernel<<<NB2, 256, 0, stream>>>(dists, P, T2b, out);
}